// Round 4
// baseline (106.495 us; speedup 1.0000x reference)
//
#include <hip/hip_runtime.h>

namespace {

constexpr int B = 4, LX = 512, LM = 512, D = 256;
// Fold 2*log2(e) into the projection: tanh(u) = 1 - 2/(1+exp2(KSCALE*u))
constexpr float KSCALE = 2.8853900817779268f;
constexpr float CLAMP = 15.0f; // E in [2^-15,2^15] -> den <= 2^120 finite

typedef __attribute__((ext_vector_type(8))) short short8;
typedef __attribute__((ext_vector_type(4))) float f32x4;

__device__ __forceinline__ unsigned bfbits(float f) {
    unsigned u = __float_as_uint(f);
    u += 0x7FFFu + ((u >> 16) & 1u);
    return u >> 16;
}
__device__ __forceinline__ int pack2(float a, float b) {
    return (int)(bfbits(a) | (bfbits(b) << 16));
}

// ---------------------------------------------------------------------------
// prep_fill: (a) fill out with -10000 (1024 blocks x 256 thr x 1 float4);
// (b) block 0: wave w ballot-compacts mask row b=w into midx[b][0..Nb),
//     pads the rest with 0, stores cnt[b]=Nb;
// (c) block 1, wave 0: sumWt = sum(Wt) -> scalar in ws.
// ---------------------------------------------------------------------------
__global__ __launch_bounds__(256) void prep_fill(
    const int* __restrict__ mask, const float* __restrict__ Wt,
    float* __restrict__ out, unsigned short* __restrict__ midx,
    int* __restrict__ cnt, float* __restrict__ sumWt)
{
    const int tid = threadIdx.x;
    float4* o4 = (float4*)out;
    o4[(size_t)blockIdx.x * 256 + tid] =
        make_float4(-10000.f, -10000.f, -10000.f, -10000.f);

    if (blockIdx.x == 0) {
        const int w = tid >> 6, lane = tid & 63;   // wave w handles batch b=w
        const unsigned long long lmask = (1ULL << lane) - 1ULL;
        int basec = 0;
#pragma unroll
        for (int k = 0; k < 8; ++k) {
            const int i = k * 64 + lane;
            const int mv = mask[w * LM + i];
            const unsigned long long bal = __ballot(mv != 0);
            const int pos = basec + (int)__popcll(bal & lmask);
            if (mv) midx[w * LM + pos] = (unsigned short)i;
            basec += (int)__popcll(bal);
        }
        for (int j = basec + lane; j < LM; j += 64) midx[w * LM + j] = 0;
        if (lane == 0) cnt[w] = basec;
    } else if (blockIdx.x == 1 && tid < 64) {
        float v = Wt[tid] + Wt[tid + 64] + Wt[tid + 128] + Wt[tid + 192];
#pragma unroll
        for (int off = 32; off; off >>= 1) v += __shfl_xor(v, off);
        if (tid == 0) *sumWt = v;
    }
}

// ---------------------------------------------------------------------------
// proj_mfma: combined GEMM, M=4096 (rows 0..2047 = x@W1^T + b1,
// rows 2048..4095 = mem@W2^T), N=256, K=256. Output E = exp2(clamp(KSCALE*y)).
// 32x64 tile/block, 4 waves; coalesced float4 loads -> bf16 LDS ->
// ds_read_b128 fragments -> mfma_f32_16x16x32_bf16. Grid (128,4) = 2/CU.
// ---------------------------------------------------------------------------
__global__ __launch_bounds__(256) void proj_mfma(
    const float* __restrict__ x, const float* __restrict__ mem,
    const float* __restrict__ W1, const float* __restrict__ b1v,
    const float* __restrict__ W2, float* __restrict__ E1, float* __restrict__ E2)
{
    const int tid = threadIdx.x;
    const int m0c = blockIdx.x * 32;
    const int e0  = blockIdx.y * 64;
    const int z   = m0c >= 2048;
    const int r0  = z ? (m0c - 2048) : m0c;
    const float* __restrict__ A = (z ? mem : x) + (size_t)r0 * D;
    const float* __restrict__ W = z ? W2 : W1;
    float* __restrict__ E = z ? E2 : E1;

    __shared__ short sA[32][40];
    __shared__ short sW[64][40];

    const int wv = tid >> 6, lane = tid & 63;
    const int lr = lane & 15, quad = lane >> 4;
    const int g   = wv & 1;
    const int cg0 = (wv >> 1) * 2;
    const int srA = tid >> 3;
    const int scA = (tid & 7) * 4;

    f32x4 acc0 = {0.f, 0.f, 0.f, 0.f};
    f32x4 acc1 = {0.f, 0.f, 0.f, 0.f};

    for (int kc = 0; kc < D; kc += 32) {
        float4 av = *(const float4*)&A[(size_t)srA * D + kc + scA];
        float4 w0 = *(const float4*)&W[(size_t)(e0 + srA) * D + kc + scA];
        float4 w1 = *(const float4*)&W[(size_t)(e0 + 32 + srA) * D + kc + scA];
        __syncthreads();
        *(int2*)&sA[srA][scA]      = make_int2(pack2(av.x, av.y), pack2(av.z, av.w));
        *(int2*)&sW[srA][scA]      = make_int2(pack2(w0.x, w0.y), pack2(w0.z, w0.w));
        *(int2*)&sW[srA + 32][scA] = make_int2(pack2(w1.x, w1.y), pack2(w1.z, w1.w));
        __syncthreads();
        short8 af  = *(const short8*)&sA[g * 16 + lr][quad * 8];
        short8 bf0 = *(const short8*)&sW[cg0 * 16 + lr][quad * 8];
        short8 bf1 = *(const short8*)&sW[cg0 * 16 + 16 + lr][quad * 8];
        acc0 = __builtin_amdgcn_mfma_f32_16x16x32_bf16(af, bf0, acc0, 0, 0, 0);
        acc1 = __builtin_amdgcn_mfma_f32_16x16x32_bf16(af, bf1, acc1, 0, 0, 0);
    }

    const float bias0 = z ? 0.f : b1v[e0 + cg0 * 16 + lr];
    const float bias1 = z ? 0.f : b1v[e0 + cg0 * 16 + 16 + lr];
#pragma unroll
    for (int reg = 0; reg < 4; ++reg) {
        const int row = r0 + g * 16 + quad * 4 + reg;
        float a0 = KSCALE * (acc0[reg] + bias0);
        float a1 = KSCALE * (acc1[reg] + bias1);
        a0 = fminf(fmaxf(a0, -CLAMP), CLAMP);
        a1 = fminf(fmaxf(a1, -CLAMP), CLAMP);
        E[(size_t)row * D + e0 + cg0 * 16 + lr]      = __builtin_amdgcn_exp2f(a0);
        E[(size_t)row * D + e0 + cg0 * 16 + 16 + lr] = __builtin_amdgcn_exp2f(a1);
    }
}

// ---------------------------------------------------------------------------
// tanh_score v3 (mask-compacted): only active m-columns (j < Nb) computed.
// S = sumWt - 2*sum_d Wt[d]/(1+E1[x,d]E2[m,d]); inactive already -10000.
// 32(x) x 64(compact-m) tile, 2x4/thread, D-chunks of 64, LDS stride 68.
// Grid (16 x0, 4 b, 8 jtile): jtile slowest -> ~1 active tile per CU.
// ---------------------------------------------------------------------------
__global__ __launch_bounds__(256) void tanh_score_kernel(
    const float* __restrict__ e1p, const float* __restrict__ e2p,
    const float* __restrict__ Wt, const unsigned short* __restrict__ midx,
    const int* __restrict__ cnt, const float* __restrict__ sumWt,
    float* __restrict__ out)
{
    const int tid = threadIdx.x;
    const int x0 = blockIdx.x * 32;
    const int b  = blockIdx.y;
    const int j0 = blockIdx.z * 64;
    const int Nb = cnt[b];
    if (j0 >= Nb) return;

    __shared__ float sA[32][68];
    __shared__ float sB[64][68];

    const int tx = tid & 15, ty = tid >> 4;
    const int rA = tid >> 3, cA = (tid & 7) * 8;
    const int rB = tid >> 2, cB = (tid & 3) * 16;
    const int growB = midx[b * LM + j0 + rB];  // padded -> always valid row

    const float* gAbase = &e1p[((size_t)b * LX + x0 + rA) * D + cA];
    const float* gBbase = &e2p[((size_t)b * LM + growB) * D + cB];

    float a00 = 0.f, a01 = 0.f, a02 = 0.f, a03 = 0.f;
    float a10 = 0.f, a11 = 0.f, a12 = 0.f, a13 = 0.f;

    for (int c = 0; c < 4; ++c) {
        const int dB = c * 64;
        float4 A0 = *(const float4*)(gAbase + dB + 0);
        float4 A1 = *(const float4*)(gAbase + dB + 4);
        float4 B0 = *(const float4*)(gBbase + dB + 0);
        float4 B1 = *(const float4*)(gBbase + dB + 4);
        float4 B2 = *(const float4*)(gBbase + dB + 8);
        float4 B3 = *(const float4*)(gBbase + dB + 12);
        __syncthreads();
        *(float4*)&sA[rA][cA + 0] = A0;
        *(float4*)&sA[rA][cA + 4] = A1;
        *(float4*)&sB[rB][cB + 0]  = B0;
        *(float4*)&sB[rB][cB + 4]  = B1;
        *(float4*)&sB[rB][cB + 8]  = B2;
        *(float4*)&sB[rB][cB + 12] = B3;
        __syncthreads();

#pragma unroll 4
        for (int d = 0; d < 64; d += 4) {
            const float4 wq  = *(const float4*)&Wt[dB + d]; // uniform -> s_load
            const float4 ra0 = *(const float4*)&sA[ty][d];
            const float4 ra1 = *(const float4*)&sA[ty + 16][d];
            const float4 rb0 = *(const float4*)&sB[tx][d];
            const float4 rb1 = *(const float4*)&sB[tx + 16][d];
            const float4 rb2 = *(const float4*)&sB[tx + 32][d];
            const float4 rb3 = *(const float4*)&sB[tx + 48][d];

#define QUAD(ra, rb, accv) {                                           \
            const float A0_ = fmaf((ra).x, (rb).x, 1.f);               \
            const float A1_ = fmaf((ra).y, (rb).y, 1.f);               \
            const float A2_ = fmaf((ra).z, (rb).z, 1.f);               \
            const float A3_ = fmaf((ra).w, (rb).w, 1.f);               \
            const float L_ = A0_ * A1_, R_ = A2_ * A3_;                \
            const float den_ = L_ * R_;                                \
            const float t0_ = fmaf(wq.y, A0_, wq.x * A1_);             \
            const float t1_ = fmaf(wq.w, A2_, wq.z * A3_);             \
            const float N_ = fmaf(t1_, L_, t0_ * R_);                  \
            (accv) = fmaf(N_, __builtin_amdgcn_rcpf(den_), (accv)); }

            QUAD(ra0, rb0, a00); QUAD(ra0, rb1, a01);
            QUAD(ra0, rb2, a02); QUAD(ra0, rb3, a03);
            QUAD(ra1, rb0, a10); QUAD(ra1, rb1, a11);
            QUAD(ra1, rb2, a12); QUAD(ra1, rb3, a13);
#undef QUAD
        }
    }

    const float sW = *sumWt;
    const int xA = x0 + ty, xB = x0 + ty + 16;
    const float s0[4] = {sW - 2.f * a00, sW - 2.f * a01,
                         sW - 2.f * a02, sW - 2.f * a03};
    const float s1[4] = {sW - 2.f * a10, sW - 2.f * a11,
                         sW - 2.f * a12, sW - 2.f * a13};
#pragma unroll
    for (int k = 0; k < 4; ++k) {
        const int j = j0 + tx + 16 * k;
        if (j < Nb) {
            const int m = midx[b * LM + j];
            out[((size_t)b * LX + xA) * LM + m] = s0[k];
            out[((size_t)b * LX + xB) * LM + m] = s1[k];
        }
    }
}

} // namespace

extern "C" void kernel_launch(void* const* d_in, const int* in_sizes, int n_in,
                              void* d_out, int out_size, void* d_ws, size_t ws_size,
                              hipStream_t stream)
{
    const float* x    = (const float*)d_in[0];
    const float* mem  = (const float*)d_in[1];
    const int*   mask = (const int*)d_in[2];
    const float* W1   = (const float*)d_in[3];
    const float* b1   = (const float*)d_in[4];
    const float* W2   = (const float*)d_in[5];
    const float* Wt   = (const float*)d_in[6];
    float* out = (float*)d_out;

    float* E1 = (float*)d_ws;                       // (2048,256) f32
    float* E2 = E1 + (size_t)B * LX * D;            // (2048,256) f32
    unsigned short* midx = (unsigned short*)(E2 + (size_t)B * LM * D); // (4,512)
    int* cnt = (int*)(midx + B * LM);               // (4,)
    float* sumWt = (float*)(cnt + B);               // scalar

    prep_fill<<<dim3(1024), 256, 0, stream>>>(mask, Wt, out, midx, cnt, sumWt);

    proj_mfma<<<dim3(128, 4), 256, 0, stream>>>(x, mem, W1, b1, W2, E1, E2);

    tanh_score_kernel<<<dim3(LX / 32, B, LM / 64), 256, 0, stream>>>(
        E1, E2, Wt, midx, cnt, sumWt, out);
}

// Round 5
// 104.518 us; speedup vs baseline: 1.0189x; 1.0189x over previous
//
#include <hip/hip_runtime.h>

namespace {

constexpr int B = 4, LX = 512, LM = 512, D = 256;
// Fold 2*log2(e) into the projection: tanh(u) = 1 - 2/(1+exp2(KSCALE*u))
constexpr float KSCALE = 2.8853900817779268f;
// exp2-arg clamp: E in [2^-7.5, 2^7.5] -> A=1+E1E2 <= ~2^15 -> 8-term den <= 2^120.
// Saturation error <= 1-tanh(7.5/KSCALE)=0.011 per term, absmax ~0.1 << 199.7.
constexpr float CLAMP = 7.5f;

typedef __attribute__((ext_vector_type(8))) short short8;
typedef __attribute__((ext_vector_type(4))) float f32x4;
typedef __attribute__((ext_vector_type(2))) float f32x2;

__device__ __forceinline__ unsigned bfbits(float f) {
    unsigned u = __float_as_uint(f);
    u += 0x7FFFu + ((u >> 16) & 1u);
    return u >> 16;
}
__device__ __forceinline__ int pack2(float a, float b) {
    return (int)(bfbits(a) | (bfbits(b) << 16));
}
// paired-bf16 u32 -> float2 {lo-row, hi-row}; shl/and are exact bf16->f32
__device__ __forceinline__ f32x2 up2(unsigned u) {
    f32x2 r;
    r.x = __uint_as_float(u << 16);
    r.y = __uint_as_float(u & 0xFFFF0000u);
    return r;
}

// ---------------------------------------------------------------------------
// proj_mfma: combined GEMM (rows 0..2047 = x@W1^T+b1, 2048..4095 = mem@W2^T),
// epilogue writes E = bf16(exp2(clamp(KSCALE*y))) in PAIR-PACKED layout:
//   u32[ ((row>>5)*16 + (row&15))*256 + e ] = {lo: half0 row, hi: half1 row}
// (halves = row&16). 32x64 tile/block, MFMA 16x16x32 bf16 via LDS staging.
// ---------------------------------------------------------------------------
__global__ __launch_bounds__(256) void proj_mfma(
    const float* __restrict__ x, const float* __restrict__ mem,
    const float* __restrict__ W1, const float* __restrict__ b1v,
    const float* __restrict__ W2,
    unsigned short* __restrict__ E1h, unsigned short* __restrict__ E2h)
{
    const int tid = threadIdx.x;
    const int m0c = blockIdx.x * 32;
    const int e0  = blockIdx.y * 64;
    const int z   = m0c >= 2048;
    const int r0  = z ? (m0c - 2048) : m0c;
    const float* __restrict__ A = (z ? mem : x) + (size_t)r0 * D;
    const float* __restrict__ W = z ? W2 : W1;
    unsigned short* __restrict__ Eh = z ? E2h : E1h;

    __shared__ short sA[32][40];
    __shared__ short sW[64][40];

    const int wv = tid >> 6, lane = tid & 63;
    const int lr = lane & 15, quad = lane >> 4;
    const int g   = wv & 1;              // row half (0: rows 0-15, 1: 16-31)
    const int cg0 = (wv >> 1) * 2;
    const int srA = tid >> 3;
    const int scA = (tid & 7) * 4;

    f32x4 acc0 = {0.f, 0.f, 0.f, 0.f};
    f32x4 acc1 = {0.f, 0.f, 0.f, 0.f};

    for (int kc = 0; kc < D; kc += 32) {
        float4 av = *(const float4*)&A[(size_t)srA * D + kc + scA];
        float4 w0 = *(const float4*)&W[(size_t)(e0 + srA) * D + kc + scA];
        float4 w1 = *(const float4*)&W[(size_t)(e0 + 32 + srA) * D + kc + scA];
        __syncthreads();
        *(int2*)&sA[srA][scA]      = make_int2(pack2(av.x, av.y), pack2(av.z, av.w));
        *(int2*)&sW[srA][scA]      = make_int2(pack2(w0.x, w0.y), pack2(w0.z, w0.w));
        *(int2*)&sW[srA + 32][scA] = make_int2(pack2(w1.x, w1.y), pack2(w1.z, w1.w));
        __syncthreads();
        short8 af  = *(const short8*)&sA[g * 16 + lr][quad * 8];
        short8 bf0 = *(const short8*)&sW[cg0 * 16 + lr][quad * 8];
        short8 bf1 = *(const short8*)&sW[cg0 * 16 + 16 + lr][quad * 8];
        acc0 = __builtin_amdgcn_mfma_f32_16x16x32_bf16(af, bf0, acc0, 0, 0, 0);
        acc1 = __builtin_amdgcn_mfma_f32_16x16x32_bf16(af, bf1, acc1, 0, 0, 0);
    }

    const float bias0 = z ? 0.f : b1v[e0 + cg0 * 16 + lr];
    const float bias1 = z ? 0.f : b1v[e0 + cg0 * 16 + 16 + lr];
    const int ec0 = e0 + cg0 * 16 + lr;
#pragma unroll
    for (int reg = 0; reg < 4; ++reg) {
        const int pair = quad * 4 + reg;           // row within half
        const size_t base = (size_t)((r0 >> 5) * 16 + pair) * 256;
        float a0 = KSCALE * (acc0[reg] + bias0);
        float a1 = KSCALE * (acc1[reg] + bias1);
        a0 = fminf(fmaxf(a0, -CLAMP), CLAMP);
        a1 = fminf(fmaxf(a1, -CLAMP), CLAMP);
        Eh[(base + ec0) * 2 + g] =
            (unsigned short)bfbits(__builtin_amdgcn_exp2f(a0));
        Eh[(base + ec0 + 16) * 2 + g] =
            (unsigned short)bfbits(__builtin_amdgcn_exp2f(a1));
    }
}

// ---------------------------------------------------------------------------
// tanh_score v4: S = sumWt - 2*sum_d Wt[d]/(1+E1E2), mask at write.
// Pair-packed bf16 E: one u32 = {x-row, x-row+16} (A) or {m, m+16} (B).
// 32(x) x 64(m) tile, 256 thr, thread = x-pair(ty) x 2 m-pairs(tx / tx+16),
// both orientations via lane-swap -> 2x2 outputs per pair-combination.
// float2 (ext_vector) math -> v_pk_fma_f32; 8-term common denominator:
// 1 rcp per 8 d per output-pair. D-chunks of 128 u32 in LDS (stride 132).
// Grid (8,16,4)=512 blocks = 2/CU.
// ---------------------------------------------------------------------------
__global__ __launch_bounds__(256) void tanh_score_kernel(
    const unsigned* __restrict__ E1p, const unsigned* __restrict__ E2p,
    const float* __restrict__ Wt, const int* __restrict__ mask,
    float* __restrict__ out)
{
    const int tid = threadIdx.x;
    const int b  = blockIdx.z;
    const int x0 = blockIdx.y * 32;
    const int m0 = blockIdx.x * 64;
    const int xt = (b * LX + x0) >> 5;   // global 32-row tile index of E1p
    const int mt = (b * LM + m0) >> 5;   // global 32-row tile base of E2p

    __shared__ unsigned sA[16 * 132];
    __shared__ unsigned sB[32 * 132];

    const int tx = tid & 15, ty = tid >> 4;
    const int pA = tid >> 4, cA = (tid & 15) * 4;   // sA staging
    const int rB = tid >> 3, cB = (tid & 7) * 4;    // sB staging
    const unsigned* gA = E1p + (size_t)(xt * 16 + pA) * 256;
    const unsigned* gB = E2p + (size_t)((mt + (rB >> 4)) * 16 + (rB & 15)) * 256;

    // uniform sum of Wt (once per thread; scalar-load friendly)
    float sumW = 0.f;
#pragma unroll
    for (int i = 0; i < 256; i += 4) {
        const float4 w = *(const float4*)&Wt[i];
        sumW += (w.x + w.y) + (w.z + w.w);
    }

    f32x2 acc01s = {0.f, 0.f}, acc01w = {0.f, 0.f};
    f32x2 acc23s = {0.f, 0.f}, acc23w = {0.f, 0.f};
    const f32x2 one2 = {1.f, 1.f};

    for (int c = 0; c < 2; ++c) {
        const int dB = c * 128;
        uint4 A0 = *(const uint4*)(gA + dB + cA);
        uint4 A1 = *(const uint4*)(gA + dB + 64 + cA);
        uint4 B0 = *(const uint4*)(gB + dB + cB);
        uint4 B1 = *(const uint4*)(gB + dB + 32 + cB);
        uint4 B2 = *(const uint4*)(gB + dB + 64 + cB);
        uint4 B3 = *(const uint4*)(gB + dB + 96 + cB);
        __syncthreads();
        *(uint4*)&sA[pA * 132 + cA]      = A0;
        *(uint4*)&sA[pA * 132 + 64 + cA] = A1;
        *(uint4*)&sB[rB * 132 + cB]      = B0;
        *(uint4*)&sB[rB * 132 + 32 + cB] = B1;
        *(uint4*)&sB[rB * 132 + 64 + cB] = B2;
        *(uint4*)&sB[rB * 132 + 96 + cB] = B3;
        __syncthreads();

#pragma unroll 1
        for (int d = 0; d < 128; d += 8) {
            const uint4 ua0 = *(const uint4*)&sA[ty * 132 + d];
            const uint4 ua1 = *(const uint4*)&sA[ty * 132 + d + 4];
            const uint4 ub0 = *(const uint4*)&sB[tx * 132 + d];
            const uint4 ub1 = *(const uint4*)&sB[tx * 132 + d + 4];
            const uint4 uc0 = *(const uint4*)&sB[(16 + tx) * 132 + d];
            const uint4 uc1 = *(const uint4*)&sB[(16 + tx) * 132 + d + 4];
            const float4 w0 = *(const float4*)&Wt[dB + d];      // uniform
            const float4 w1 = *(const float4*)&Wt[dB + d + 4];

            const f32x2 a_[8] = {up2(ua0.x), up2(ua0.y), up2(ua0.z), up2(ua0.w),
                                 up2(ua1.x), up2(ua1.y), up2(ua1.z), up2(ua1.w)};
            const f32x2 p_[8] = {up2(ub0.x), up2(ub0.y), up2(ub0.z), up2(ub0.w),
                                 up2(ub1.x), up2(ub1.y), up2(ub1.z), up2(ub1.w)};
            const f32x2 q_[8] = {up2(uc0.x), up2(uc0.y), up2(uc0.z), up2(uc0.w),
                                 up2(uc1.x), up2(uc1.y), up2(uc1.z), up2(uc1.w)};
            const float wv[8] = {w0.x, w0.y, w0.z, w0.w, w1.x, w1.y, w1.z, w1.w};

#define SPL(s)  ((f32x2){(s), (s)})
#define FMA2(A_, B_, C_) __builtin_elementwise_fma((A_), (B_), (C_))
            // 8-term common denominator over a float2 lane-pair:
            // acc += (sum_j wv[j]/(1+a_j*b_j)) elementwise, ONE rcp per lane.
#define OCT(BX, accv) { \
    const f32x2 T0 = FMA2(a_[0], BX(0), one2), T1 = FMA2(a_[1], BX(1), one2); \
    const f32x2 T2 = FMA2(a_[2], BX(2), one2), T3 = FMA2(a_[3], BX(3), one2); \
    const f32x2 T4 = FMA2(a_[4], BX(4), one2), T5 = FMA2(a_[5], BX(5), one2); \
    const f32x2 T6 = FMA2(a_[6], BX(6), one2), T7 = FMA2(a_[7], BX(7), one2); \
    const f32x2 L0 = T0 * T1, L1 = T2 * T3, L2 = T4 * T5, L3 = T6 * T7;       \
    const f32x2 Q0 = L0 * L1, Q1 = L2 * L3;                                   \
    const f32x2 den = Q0 * Q1;                                                \
    const f32x2 n0 = FMA2(SPL(wv[0]), T1, SPL(wv[1]) * T0);                   \
    const f32x2 n1 = FMA2(SPL(wv[2]), T3, SPL(wv[3]) * T2);                   \
    const f32x2 n2 = FMA2(SPL(wv[4]), T5, SPL(wv[5]) * T4);                   \
    const f32x2 n3 = FMA2(SPL(wv[6]), T7, SPL(wv[7]) * T6);                   \
    const f32x2 u0 = FMA2(n0, L1, n1 * L0), u1 = FMA2(n2, L3, n3 * L2);       \
    const f32x2 N  = FMA2(u0, Q1, u1 * Q0);                                   \
    f32x2 r; r.x = __builtin_amdgcn_rcpf(den.x);                              \
             r.y = __builtin_amdgcn_rcpf(den.y);                              \
    (accv) = FMA2(N, r, (accv)); }

#define BP(i)  (p_[i])
#define BPS(i) (__builtin_shufflevector(p_[i], p_[i], 1, 0))
#define BQ(i)  (q_[i])
#define BQS(i) (__builtin_shufflevector(q_[i], q_[i], 1, 0))
            OCT(BP,  acc01s)   // (xA,g0) , (xB,g1)
            OCT(BPS, acc01w)   // (xA,g1) , (xB,g0)
            OCT(BQ,  acc23s)   // (xA,g2) , (xB,g3)
            OCT(BQS, acc23w)   // (xA,g3) , (xB,g2)
#undef BP
#undef BPS
#undef BQ
#undef BQS
#undef OCT
#undef FMA2
#undef SPL
        }
    }

    const int xA = x0 + ty, xB = x0 + 16 + ty;
    const int mmv[4] = {m0 + tx, m0 + 16 + tx, m0 + 32 + tx, m0 + 48 + tx};
    const float vA[4] = {acc01s.x, acc01w.x, acc23s.x, acc23w.x};
    const float vB[4] = {acc01w.y, acc01s.y, acc23w.y, acc23s.y};
#pragma unroll
    for (int k = 0; k < 4; ++k) {
        const bool keep = mask[b * LM + mmv[k]] != 0;
        out[((size_t)b * LX + xA) * LM + mmv[k]] =
            keep ? (sumW - 2.f * vA[k]) : -10000.f;
        out[((size_t)b * LX + xB) * LM + mmv[k]] =
            keep ? (sumW - 2.f * vB[k]) : -10000.f;
    }
}

} // namespace

extern "C" void kernel_launch(void* const* d_in, const int* in_sizes, int n_in,
                              void* d_out, int out_size, void* d_ws, size_t ws_size,
                              hipStream_t stream)
{
    const float* x    = (const float*)d_in[0];
    const float* mem  = (const float*)d_in[1];
    const int*   mask = (const int*)d_in[2];
    const float* W1   = (const float*)d_in[3];
    const float* b1   = (const float*)d_in[4];
    const float* W2   = (const float*)d_in[5];
    const float* Wt   = (const float*)d_in[6];
    float* out = (float*)d_out;

    unsigned* E1p = (unsigned*)d_ws;                 // (64 tiles,16,256) u32 pairs
    unsigned* E2p = E1p + (size_t)(B * LX / 32) * 16 * 256;

    proj_mfma<<<dim3(128, 4), 256, 0, stream>>>(
        x, mem, W1, b1, W2, (unsigned short*)E1p, (unsigned short*)E2p);

    tanh_score_kernel<<<dim3(LM / 64, LX / 32, B), 256, 0, stream>>>(
        E1p, E2p, Wt, mask, out);
}